// Round 4
// baseline (2340.262 us; speedup 1.0000x reference)
//
#include <hip/hip_runtime.h>
#include <cstdint>
#include <cstddef>

typedef __attribute__((ext_vector_type(4))) float f32x4;
typedef __attribute__((ext_vector_type(8))) short short8;
typedef __attribute__((ext_vector_type(4))) unsigned int u32x4;

static const int TS = 2048;      // sequence length
static const int DM = 2048;      // d_model
static const int NHEAD = 16, NKVH = 8, HDIM = 128;
static const int FFD = 8192;
static const int NVOC = 32000;
static const int QKVN = 4096;    // fused QKV output width (2048 q + 1024 k + 1024 v)

__device__ __forceinline__ unsigned short f2bf(float f){
  unsigned int u = __builtin_bit_cast(unsigned int, f);
  u += 0x7FFFu + ((u >> 16) & 1u);
  return (unsigned short)(u >> 16);
}
__device__ __forceinline__ float bf2f(short h){
  unsigned int u = ((unsigned int)(unsigned short)h) << 16;
  return __builtin_bit_cast(float, u);
}
__device__ __forceinline__ f32x4 mfma16(short8 a, short8 b, f32x4 c){
  return __builtin_amdgcn_mfma_f32_16x16x32_bf16(a, b, c, 0, 0, 0);
}
__device__ __forceinline__ void gload16(const void* g, void* l){
  __builtin_amdgcn_global_load_lds(
      (const __attribute__((address_space(1))) unsigned int*)g,
      (__attribute__((address_space(3))) unsigned int*)l, 16, 0, 0);
}

// ---------------- RoPE tables ----------------
__global__ void rope_tables_k(float* __restrict__ cosT, float* __restrict__ sinT){
  int idx = blockIdx.x * 256 + threadIdx.x;   // TS*64 entries
  int s = idx >> 6, j = idx & 63;
  float inv = exp2f(-(float)j * (13.287712379549449f / 64.0f)); // 10000^(-j/64)
  float ang = (float)s * inv;
  cosT[idx] = cosf(ang);
  sinT[idx] = sinf(ang);
}

// ---------------- embedding gather ----------------
__global__ void embed_k(const int* __restrict__ ids, const float* __restrict__ E,
                        float* __restrict__ h){
  int s = blockIdx.x, tid = threadIdx.x;
  long id = ids[s];
  const f32x4* src = (const f32x4*)(E + id * (long)DM);
  f32x4* dst = (f32x4*)(h + (long)s * DM);
  dst[tid] = src[tid];
  dst[tid + 256] = src[tid + 256];
}

// ---------------- RMSNorm (f32 in -> bf16 out) ----------------
__global__ void rmsnorm_k(const float* __restrict__ x, const float* __restrict__ w,
                          short* __restrict__ out){
  int s = blockIdx.x, tid = threadIdx.x;
  const float* row = x + (long)s * DM;
  f32x4 v0 = *(const f32x4*)&row[tid * 8];
  f32x4 v1 = *(const f32x4*)&row[tid * 8 + 4];
  float ss = v0[0]*v0[0] + v0[1]*v0[1] + v0[2]*v0[2] + v0[3]*v0[3]
           + v1[0]*v1[0] + v1[1]*v1[1] + v1[2]*v1[2] + v1[3]*v1[3];
  #pragma unroll
  for (int off = 32; off; off >>= 1) ss += __shfl_xor(ss, off);
  __shared__ float sred[4];
  int wave = tid >> 6, lane = tid & 63;
  if (lane == 0) sred[wave] = ss;
  __syncthreads();
  float tot = sred[0] + sred[1] + sred[2] + sred[3];
  float r = rsqrtf(tot * (1.0f / (float)DM) + 1e-5f);
  f32x4 w0 = *(const f32x4*)&w[tid * 8];
  f32x4 w1 = *(const f32x4*)&w[tid * 8 + 4];
  short8 o;
  #pragma unroll
  for (int j = 0; j < 4; j++) o[j] = (short)f2bf(v0[j] * r * w0[j]);
  #pragma unroll
  for (int j = 0; j < 4; j++) o[4 + j] = (short)f2bf(v1[j] * r * w1[j]);
  *(short8*)&out[(long)s * DM + tid * 8] = o;
}

// ---------------- weight transpose+convert: B[K][N] f32 -> Bt[N][K] bf16 ----------------
__global__ void transpose_k(const float* __restrict__ B, short* __restrict__ Bt,
                            int K, int N){
  __shared__ float t[64][65];
  int tid = threadIdx.x;
  int kb = blockIdx.y * 64, nb = blockIdx.x * 64;
  int r0 = tid >> 4, c4 = tid & 15;
  #pragma unroll
  for (int p = 0; p < 4; p++){
    int r = r0 + p * 16;
    f32x4 v = *(const f32x4*)&B[(long)(kb + r) * N + nb + c4 * 4];
    t[r][c4*4+0] = v[0]; t[r][c4*4+1] = v[1]; t[r][c4*4+2] = v[2]; t[r][c4*4+3] = v[3];
  }
  __syncthreads();
  int n0 = tid >> 3, k0 = (tid & 7) * 8;
  #pragma unroll
  for (int p = 0; p < 2; p++){
    int n = n0 + p * 32;
    short8 o;
    #pragma unroll
    for (int j = 0; j < 8; j++) o[j] = (short)f2bf(t[k0 + j][n]);
    *(short8*)&Bt[(long)(nb + n) * K + kb + k0] = o;
  }
}

// ---------------- V transpose: vsrc[s][kv*HD+d] (stride) -> vtb[kv][d][s] (bf16) ----------------
__global__ void vtrans_k(const short* __restrict__ vb, short* __restrict__ vtb, int stride){
  int s0 = blockIdx.x * 64, kv = blockIdx.y;
  int tid = threadIdx.x;
  int s = s0 + (tid & 63);
  int d0 = (tid >> 6) * 8;
  #pragma unroll
  for (int p = 0; p < 4; p++){
    int d = d0 + p * 32;
    short8 v = *(const short8*)&vb[(long)s * stride + kv * HDIM + d];
    #pragma unroll
    for (int j = 0; j < 8; j++)
      vtb[(long)(kv * HDIM + d + j) * TS + s] = v[j];
  }
}

// ---------------- RoPE apply (in-place bf16) ----------------
__global__ void rope_apply_k(short* __restrict__ buf, const float* __restrict__ cosT,
                             const float* __restrict__ sinT, int nh, int stride, int coloff){
  int idx = blockIdx.x * 256 + threadIdx.x;  // TS*nh*64
  int j = idx & 63;
  int t = idx >> 6;
  int hh = t % nh;
  int s = t / nh;
  long base = (long)s * stride + coloff + hh * HDIM + j;
  float c = cosT[s * 64 + j], sn = sinT[s * 64 + j];
  float x1 = bf2f(buf[base]), x2 = bf2f(buf[base + 64]);
  buf[base]      = (short)f2bf(x1 * c - x2 * sn);
  buf[base + 64] = (short)f2bf(x2 * c + x1 * sn);
}

// ---------------- GEMM: C[M,N] = A[M,K](bf16) x Bt[N,K](bf16) ----------------
// 128x128 tile, BK=32, 4 waves, m97 sync structure (single LDS buffer,
// __syncthreads around staging), fragment-major conflict-free LDS layout
// (pre-swizzled global source), bijective XCD swizzle + mb-fastest grid.
// EPI: 0 = f32 store, 1 = bf16 store, 2 = f32 residual add (Cf += acc),
//      3 = bf16 silu(acc), 4 = bf16 (bf2f(Xtra) * acc)
template<int EPI>
__global__ __launch_bounds__(256)
void gemm_bt(const short* __restrict__ A, const short* __restrict__ Bt,
             float* __restrict__ Cf, short* __restrict__ Cb,
             const short* __restrict__ Xtra, int N, int K){
  __shared__ short As[4096];
  __shared__ short Bs[4096];
  const int tid = threadIdx.x;
  const int wave = tid >> 6, lane = tid & 63;
  const int wr = wave >> 1, wc = wave & 1;

  // bijective XCD swizzle (m204) + mb-fastest decomposition (MT = 16)
  const int NT = N >> 7;
  const int nwg = NT << 4;
  const int wg = blockIdx.x;
  const int xcd = wg & 7, rest = wg >> 3;
  const int q = nwg >> 3, r = nwg & 7;
  const int swz = (xcd < r ? xcd * (q + 1) : r * (q + 1) + (xcd - r) * q) + rest;
  const int mb = swz & 15, nb = swz >> 4;

  // pre-swizzled global source: lane i fetches row (i&15), k-chunk (i>>4)
  const int srow = lane & 15;
  const int scol = (lane >> 4) * 8;
  const short* ApL0 = A  + (long)(mb * 128 + wave * 16 + srow) * K + scol;
  const short* ApL1 = ApL0 + (long)64 * K;
  const short* BpL0 = Bt + (long)(nb * 128 + wave * 16 + srow) * K + scol;
  const short* BpL1 = BpL0 + (long)64 * K;

  f32x4 acc[4][4] = {};
  const int fr = lane & 15, fch = lane >> 4;

  for (int kb = 0; kb < K; kb += 32){
    __syncthreads();
    gload16(ApL0 + kb, &As[wave * 512]);
    gload16(ApL1 + kb, &As[(4 + wave) * 512]);
    gload16(BpL0 + kb, &Bs[wave * 512]);
    gload16(BpL1 + kb, &Bs[(4 + wave) * 512]);
    __syncthreads();
    short8 a[4], b[4];
    #pragma unroll
    for (int m = 0; m < 4; m++)
      a[m] = *(const short8*)&As[(wr * 4 + m) * 512 + fch * 128 + fr * 8];
    #pragma unroll
    for (int n = 0; n < 4; n++)
      b[n] = *(const short8*)&Bs[(wc * 4 + n) * 512 + fch * 128 + fr * 8];
    #pragma unroll
    for (int m = 0; m < 4; m++)
      #pragma unroll
      for (int n = 0; n < 4; n++)
        acc[m][n] = mfma16(a[m], b[n], acc[m][n]);
  }

  const int rb = mb * 128 + wr * 64 + (lane >> 4) * 4;
  const int cb = nb * 128 + wc * 64 + (lane & 15);
  #pragma unroll
  for (int m = 0; m < 4; m++)
    #pragma unroll
    for (int n = 0; n < 4; n++)
      #pragma unroll
      for (int i = 0; i < 4; i++){
        long idx = (long)(rb + m * 16 + i) * N + (cb + n * 16);
        float v = acc[m][n][i];
        if constexpr (EPI == 0) Cf[idx] = v;
        else if constexpr (EPI == 1) Cb[idx] = (short)f2bf(v);
        else if constexpr (EPI == 2) Cf[idx] += v;
        else if constexpr (EPI == 3){
          float sg = 1.0f / (1.0f + __expf(-v));
          Cb[idx] = (short)f2bf(v * sg);
        } else {
          float g = bf2f(Xtra[idx]);
          Cb[idx] = (short)f2bf(g * v);
        }
      }
}

// ---------------- flash attention ----------------
// grid: (TS/64, NHEAD); 256 threads (4 waves, 16 q-rows each)
__device__ __forceinline__ int qoff(int r, int cB){ return r * 256 + (cB ^ ((r & 7) << 4)); }
__device__ __forceinline__ int voff(int d, int cB){ return d * 128 + (cB ^ ((d & 7) << 4)); }
__device__ __forceinline__ int poff(int r, int cB){ return r * 128 + (cB ^ ((r & 7) << 4)); }

__global__ __launch_bounds__(256)
void attn_k(const short* __restrict__ qb, const short* __restrict__ kb,
            const short* __restrict__ vtb, short* __restrict__ ob){
  __shared__ short Qs[64 * 128];
  __shared__ short Ks[64 * 128];
  __shared__ short Vt[128 * 64];
  __shared__ short Ps[64 * 64];
  const int tid = threadIdx.x, wave = tid >> 6, lane = tid & 63;
  const int qt = blockIdx.x, head = blockIdx.y, kvh = head >> 1;
  const float scale = 0.08838834764831845f;  // 1/sqrt(128)

  // stage Q (once) — q lives in fused qkv buffer, row stride QKVN
  {
    int r0 = tid >> 4, c16 = tid & 15;
    #pragma unroll
    for (int p = 0; p < 4; p++){
      int r = r0 + p * 16;
      u32x4 v = *(const u32x4*)&qb[(long)(qt * 64 + r) * QKVN + head * HDIM + c16 * 8];
      *(u32x4*)((char*)Qs + qoff(r, c16 * 16)) = v;
    }
  }

  float mrun[4] = {-1e30f, -1e30f, -1e30f, -1e30f};
  float lrun[4] = {0.f, 0.f, 0.f, 0.f};
  f32x4 accO[8] = {};

  for (int kt = 0; kt <= qt; kt++){
    __syncthreads();
    {
      int r0 = tid >> 4, c16 = tid & 15;
      #pragma unroll
      for (int p = 0; p < 4; p++){
        int r = r0 + p * 16;
        u32x4 v = *(const u32x4*)&kb[(long)(kt * 64 + r) * QKVN + kvh * HDIM + c16 * 8];
        *(u32x4*)((char*)Ks + qoff(r, c16 * 16)) = v;
      }
      int vr0 = tid >> 3, vc = tid & 7;
      #pragma unroll
      for (int p = 0; p < 4; p++){
        int d = vr0 + p * 32;
        u32x4 v = *(const u32x4*)&vtb[(long)(kvh * HDIM + d) * TS + kt * 64 + vc * 8];
        *(u32x4*)((char*)Vt + voff(d, vc * 16)) = v;
      }
    }
    __syncthreads();

    // QK^T : wave's 16 q-rows x 64 keys
    f32x4 sacc[4] = {};
    #pragma unroll
    for (int k4 = 0; k4 < 4; k4++){
      short8 a = *(const short8*)((const char*)Qs +
                   qoff(wave * 16 + (lane & 15), k4 * 64 + (lane >> 4) * 16));
      #pragma unroll
      for (int n = 0; n < 4; n++){
        short8 b = *(const short8*)((const char*)Ks +
                     qoff(n * 16 + (lane & 15), k4 * 64 + (lane >> 4) * 16));
        sacc[n] = mfma16(a, b, sacc[n]);
      }
    }

    // scale + causal mask + online softmax
    const bool diag = (kt == qt);
    float mt[4] = {-1e30f, -1e30f, -1e30f, -1e30f};
    #pragma unroll
    for (int n = 0; n < 4; n++)
      #pragma unroll
      for (int i = 0; i < 4; i++){
        float v = sacc[n][i] * scale;
        if (diag){
          int r = (lane >> 4) * 4 + i + wave * 16;
          int c = n * 16 + (lane & 15);
          if (c > r) v = -1e30f;
        }
        sacc[n][i] = v;
        mt[i] = fmaxf(mt[i], v);
      }
    #pragma unroll
    for (int off = 1; off < 16; off <<= 1)
      #pragma unroll
      for (int i = 0; i < 4; i++) mt[i] = fmaxf(mt[i], __shfl_xor(mt[i], off));
    float alpha[4], rsum[4];
    #pragma unroll
    for (int i = 0; i < 4; i++){
      float mn = fmaxf(mrun[i], mt[i]);
      alpha[i] = __expf(mrun[i] - mn);
      mrun[i] = mn;
      rsum[i] = 0.f;
    }
    #pragma unroll
    for (int n = 0; n < 4; n++)
      #pragma unroll
      for (int i = 0; i < 4; i++){
        float p = __expf(sacc[n][i] - mrun[i]);
        sacc[n][i] = p;
        rsum[i] += p;
      }
    #pragma unroll
    for (int off = 1; off < 16; off <<= 1)
      #pragma unroll
      for (int i = 0; i < 4; i++) rsum[i] += __shfl_xor(rsum[i], off);
    #pragma unroll
    for (int i = 0; i < 4; i++) lrun[i] = lrun[i] * alpha[i] + rsum[i];

    // write P (own wave rows only -> no cross-wave barrier needed)
    #pragma unroll
    for (int n = 0; n < 4; n++)
      #pragma unroll
      for (int i = 0; i < 4; i++){
        int r = wave * 16 + (lane >> 4) * 4 + i;
        int c = n * 16 + (lane & 15);
        *(short*)((char*)Ps + poff(r, c * 2)) = (short)f2bf(sacc[n][i]);
      }

    // rescale O, then PV
    #pragma unroll
    for (int n = 0; n < 8; n++)
      #pragma unroll
      for (int i = 0; i < 4; i++) accO[n][i] *= alpha[i];
    #pragma unroll
    for (int ks = 0; ks < 2; ks++){
      short8 a = *(const short8*)((const char*)Ps +
                   poff(wave * 16 + (lane & 15), ks * 64 + (lane >> 4) * 16));
      #pragma unroll
      for (int n = 0; n < 8; n++){
        short8 b = *(const short8*)((const char*)Vt +
                     voff(n * 16 + (lane & 15), ks * 64 + (lane >> 4) * 16));
        accO[n] = mfma16(a, b, accO[n]);
      }
    }
  }

  // epilogue: O /= l, write bf16
  #pragma unroll
  for (int i = 0; i < 4; i++){
    float inv = 1.0f / lrun[i];
    int r = qt * 64 + wave * 16 + (lane >> 4) * 4 + i;
    #pragma unroll
    for (int n = 0; n < 8; n++){
      int c = head * HDIM + n * 16 + (lane & 15);
      ob[(long)r * DM + c] = (short)f2bf(accO[n][i] * inv);
    }
  }
}

// ---------------- host ----------------
extern "C" void kernel_launch(void* const* d_in, const int* in_sizes, int n_in,
                              void* d_out, int out_size, void* d_ws, size_t ws_size,
                              hipStream_t stream){
  (void)in_sizes; (void)n_in; (void)out_size; (void)ws_size;
  const int*   ids = (const int*)d_in[0];
  const float* E   = (const float*)d_in[1];
  const float* Wq  = (const float*)d_in[2];
  const float* Wk  = (const float*)d_in[3];
  const float* Wv  = (const float*)d_in[4];
  const float* Wo  = (const float*)d_in[5];
  const float* Wg  = (const float*)d_in[6];
  const float* Wu  = (const float*)d_in[7];
  const float* Wd  = (const float*)d_in[8];
  const float* nA  = (const float*)d_in[9];
  const float* nM  = (const float*)d_in[10];
  const float* nF  = (const float*)d_in[11];
  const float* LMH = (const float*)d_in[12];
  float* out = (float*)d_out;

  char* ws = (char*)d_ws;
  size_t off = 0;
  auto alloc = [&](size_t bytes){ void* p = ws + off; off += (bytes + 255) & ~(size_t)255; return p; };
  float* h    = (float*)alloc((size_t)TS * DM * 4);
  short* xb   = (short*)alloc((size_t)TS * DM * 2);
  short* qkvb = (short*)alloc((size_t)TS * QKVN * 2);     // [S][4096]: q | k | v
  short* vtb  = (short*)alloc((size_t)NKVH * HDIM * TS * 2);
  short* obuf = (short*)alloc((size_t)TS * DM * 2);
  short* sg   = (short*)alloc((size_t)TS * FFD * 2);
  short* actb = (short*)alloc((size_t)TS * FFD * 2);
  float* cosT = (float*)alloc((size_t)TS * 64 * 4);
  float* sinT = (float*)alloc((size_t)TS * 64 * 4);
  short* wT   = (short*)alloc((size_t)NVOC * DM * 2);

  rope_tables_k<<<512, 256, 0, stream>>>(cosT, sinT);
  embed_k<<<TS, 256, 0, stream>>>(ids, E, h);

  for (int l = 0; l < 2; l++){
    rmsnorm_k<<<TS, 256, 0, stream>>>(h, nA + (size_t)l * DM, xb);
    // fused QKV: Bt rows [0,2048)=Wq^T, [2048,3072)=Wk^T, [3072,4096)=Wv^T
    transpose_k<<<dim3(32, 32), 256, 0, stream>>>(Wq + (size_t)l * DM * DM, wT, DM, DM);
    transpose_k<<<dim3(16, 32), 256, 0, stream>>>(Wk + (size_t)l * DM * 1024, wT + (size_t)2048 * DM, DM, 1024);
    transpose_k<<<dim3(16, 32), 256, 0, stream>>>(Wv + (size_t)l * DM * 1024, wT + (size_t)3072 * DM, DM, 1024);
    gemm_bt<1><<<512, 256, 0, stream>>>(xb, wT, nullptr, qkvb, nullptr, QKVN, DM);
    // RoPE (in place on bf16) on q and k slices of qkv buffer; V transpose
    rope_apply_k<<<8192, 256, 0, stream>>>(qkvb, cosT, sinT, NHEAD, QKVN, 0);
    rope_apply_k<<<4096, 256, 0, stream>>>(qkvb, cosT, sinT, NKVH, QKVN, 2048);
    vtrans_k<<<dim3(32, 8), 256, 0, stream>>>(qkvb + 3072, vtb, QKVN);
    // attention
    attn_k<<<dim3(32, 16), 256, 0, stream>>>(qkvb, qkvb + 2048, vtb, obuf);
    // h += o @ Wo[l]
    transpose_k<<<dim3(32, 32), 256, 0, stream>>>(Wo + (size_t)l * DM * DM, wT, DM, DM);
    gemm_bt<2><<<256, 256, 0, stream>>>(obuf, wT, h, nullptr, nullptr, DM, DM);
    // MLP
    rmsnorm_k<<<TS, 256, 0, stream>>>(h, nM + (size_t)l * DM, xb);
    transpose_k<<<dim3(128, 32), 256, 0, stream>>>(Wg + (size_t)l * DM * FFD, wT, DM, FFD);
    gemm_bt<3><<<1024, 256, 0, stream>>>(xb, wT, nullptr, sg, nullptr, FFD, DM);
    transpose_k<<<dim3(128, 32), 256, 0, stream>>>(Wu + (size_t)l * DM * FFD, wT, DM, FFD);
    gemm_bt<4><<<1024, 256, 0, stream>>>(xb, wT, nullptr, actb, sg, FFD, DM);
    transpose_k<<<dim3(32, 128), 256, 0, stream>>>(Wd + (size_t)l * FFD * DM, wT, FFD, DM);
    gemm_bt<2><<<256, 256, 0, stream>>>(actb, wT, h, nullptr, nullptr, DM, FFD);
  }

  rmsnorm_k<<<TS, 256, 0, stream>>>(h, nF, xb);
  transpose_k<<<dim3(500, 32), 256, 0, stream>>>(LMH, wT, DM, NVOC);
  gemm_bt<0><<<4000, 256, 0, stream>>>(xb, wT, out, nullptr, nullptr, NVOC, DM);
}

// Round 5
// 1837.694 us; speedup vs baseline: 1.2735x; 1.2735x over previous
//
#include <hip/hip_runtime.h>
#include <cstdint>
#include <cstddef>

typedef __attribute__((ext_vector_type(4))) float f32x4;
typedef __attribute__((ext_vector_type(8))) short short8;
typedef __attribute__((ext_vector_type(4))) unsigned int u32x4;

static const int TS = 2048;      // sequence length
static const int DM = 2048;      // d_model
static const int NHEAD = 16, NKVH = 8, HDIM = 128;
static const int FFD = 8192;
static const int NVOC = 32000;
static const int QKVN = 4096;    // fused QKV output width (2048 q + 1024 k + 1024 v)

__device__ __forceinline__ unsigned short f2bf(float f){
  unsigned int u = __builtin_bit_cast(unsigned int, f);
  u += 0x7FFFu + ((u >> 16) & 1u);
  return (unsigned short)(u >> 16);
}
__device__ __forceinline__ float bf2f(short h){
  unsigned int u = ((unsigned int)(unsigned short)h) << 16;
  return __builtin_bit_cast(float, u);
}
__device__ __forceinline__ f32x4 mfma16(short8 a, short8 b, f32x4 c){
  return __builtin_amdgcn_mfma_f32_16x16x32_bf16(a, b, c, 0, 0, 0);
}
__device__ __forceinline__ void gload16(const void* g, void* l){
  __builtin_amdgcn_global_load_lds(
      (const __attribute__((address_space(1))) unsigned int*)g,
      (__attribute__((address_space(3))) unsigned int*)l, 16, 0, 0);
}

// ---------------- RoPE tables ----------------
__global__ void rope_tables_k(float* __restrict__ cosT, float* __restrict__ sinT){
  int idx = blockIdx.x * 256 + threadIdx.x;   // TS*64 entries
  int s = idx >> 6, j = idx & 63;
  float inv = exp2f(-(float)j * (13.287712379549449f / 64.0f)); // 10000^(-j/64)
  float ang = (float)s * inv;
  cosT[idx] = cosf(ang);
  sinT[idx] = sinf(ang);
}

// ---------------- embedding gather ----------------
__global__ void embed_k(const int* __restrict__ ids, const float* __restrict__ E,
                        float* __restrict__ h){
  int s = blockIdx.x, tid = threadIdx.x;
  long id = ids[s];
  const f32x4* src = (const f32x4*)(E + id * (long)DM);
  f32x4* dst = (f32x4*)(h + (long)s * DM);
  dst[tid] = src[tid];
  dst[tid + 256] = src[tid + 256];
}

// ---------------- RMSNorm (f32 in -> bf16 out) ----------------
__global__ void rmsnorm_k(const float* __restrict__ x, const float* __restrict__ w,
                          short* __restrict__ out){
  int s = blockIdx.x, tid = threadIdx.x;
  const float* row = x + (long)s * DM;
  f32x4 v0 = *(const f32x4*)&row[tid * 8];
  f32x4 v1 = *(const f32x4*)&row[tid * 8 + 4];
  float ss = v0[0]*v0[0] + v0[1]*v0[1] + v0[2]*v0[2] + v0[3]*v0[3]
           + v1[0]*v1[0] + v1[1]*v1[1] + v1[2]*v1[2] + v1[3]*v1[3];
  #pragma unroll
  for (int off = 32; off; off >>= 1) ss += __shfl_xor(ss, off);
  __shared__ float sred[4];
  int wave = tid >> 6, lane = tid & 63;
  if (lane == 0) sred[wave] = ss;
  __syncthreads();
  float tot = sred[0] + sred[1] + sred[2] + sred[3];
  float r = rsqrtf(tot * (1.0f / (float)DM) + 1e-5f);
  f32x4 w0 = *(const f32x4*)&w[tid * 8];
  f32x4 w1 = *(const f32x4*)&w[tid * 8 + 4];
  short8 o;
  #pragma unroll
  for (int j = 0; j < 4; j++) o[j] = (short)f2bf(v0[j] * r * w0[j]);
  #pragma unroll
  for (int j = 0; j < 4; j++) o[4 + j] = (short)f2bf(v1[j] * r * w1[j]);
  *(short8*)&out[(long)s * DM + tid * 8] = o;
}

// ---------------- weight transpose+convert: B[K][N] f32 -> Bt[N][K] bf16 ----------------
__global__ void transpose_k(const float* __restrict__ B, short* __restrict__ Bt,
                            int K, int N){
  __shared__ float t[64][65];
  int tid = threadIdx.x;
  int kb = blockIdx.y * 64, nb = blockIdx.x * 64;
  int r0 = tid >> 4, c4 = tid & 15;
  #pragma unroll
  for (int p = 0; p < 4; p++){
    int r = r0 + p * 16;
    f32x4 v = *(const f32x4*)&B[(long)(kb + r) * N + nb + c4 * 4];
    t[r][c4*4+0] = v[0]; t[r][c4*4+1] = v[1]; t[r][c4*4+2] = v[2]; t[r][c4*4+3] = v[3];
  }
  __syncthreads();
  int n0 = tid >> 3, k0 = (tid & 7) * 8;
  #pragma unroll
  for (int p = 0; p < 2; p++){
    int n = n0 + p * 32;
    short8 o;
    #pragma unroll
    for (int j = 0; j < 8; j++) o[j] = (short)f2bf(t[k0 + j][n]);
    *(short8*)&Bt[(long)(nb + n) * K + kb + k0] = o;
  }
}

// ---------------- V transpose: vsrc[s][kv*HD+d] (stride) -> vtb[kv][d][s] (bf16) ----------------
__global__ void vtrans_k(const short* __restrict__ vb, short* __restrict__ vtb, int stride){
  int s0 = blockIdx.x * 64, kv = blockIdx.y;
  int tid = threadIdx.x;
  int s = s0 + (tid & 63);
  int d0 = (tid >> 6) * 8;
  #pragma unroll
  for (int p = 0; p < 4; p++){
    int d = d0 + p * 32;
    short8 v = *(const short8*)&vb[(long)s * stride + kv * HDIM + d];
    #pragma unroll
    for (int j = 0; j < 8; j++)
      vtb[(long)(kv * HDIM + d + j) * TS + s] = v[j];
  }
}

// ---------------- RoPE apply (in-place bf16) ----------------
__global__ void rope_apply_k(short* __restrict__ buf, const float* __restrict__ cosT,
                             const float* __restrict__ sinT, int nh, int stride, int coloff){
  int idx = blockIdx.x * 256 + threadIdx.x;  // TS*nh*64
  int j = idx & 63;
  int t = idx >> 6;
  int hh = t % nh;
  int s = t / nh;
  long base = (long)s * stride + coloff + hh * HDIM + j;
  float c = cosT[s * 64 + j], sn = sinT[s * 64 + j];
  float x1 = bf2f(buf[base]), x2 = bf2f(buf[base + 64]);
  buf[base]      = (short)f2bf(x1 * c - x2 * sn);
  buf[base + 64] = (short)f2bf(x2 * c + x1 * sn);
}

// ================= 256x256 8-phase GEMM (T2-layout + T3/T4/T5) =================
// C[M,N] = A[M,K](bf16) x Bt[N,K](bf16).  512 threads = 8 waves (2Mx4N),
// BK=64, 2 K-tiles per iteration, 128 KiB LDS (2 buf x (A 32K + B 32K)),
// fragment-major conflict-free subtiles (16 rows x 32 k = 1 KiB), staged via
// global_load_lds with per-lane pre-swizzled source; counted vmcnt(6) at
// phases 4/8; raw s_barrier pairs; setprio around MFMA clusters.
// EPI: 0 = f32 store, 1 = bf16 store, 3 = bf16 silu, 4 = bf16 Xtra*acc
template<int EPI>
__global__ __launch_bounds__(512, 2)
void gemm256(const short* __restrict__ A, const short* __restrict__ Bt,
             float* __restrict__ Cf, short* __restrict__ Cb,
             const short* __restrict__ Xtra, int N, int K){
  __shared__ short lds[2][2][16384];   // [buf][op][256 rows x 64 k], subtiled
  const int tid = threadIdx.x;
  const int wid = tid >> 6, lane = tid & 63;
  const int wr = wid >> 2, wc = wid & 3;
  const int mb = blockIdx.y, nb = blockIdx.x;
  const int fr = lane & 15, fch = lane >> 4;
  const int nt = K >> 6;               // K-tiles of 64 (even for all our shapes)
  const int nIter = nt >> 1;

  // per-lane global staging base: row (+fr), k-chunk (+fch*8)
  const short* Abase = A  + (long)(mb * 256 + fr) * K + fch * 8;
  const short* Bbase = Bt + (long)(nb * 256 + fr) * K + fch * 8;
  const int gA = ((wid >> 2) << 3) | (wid & 3);   // A alpha-unit group for this wave
  const int gB = ((wid >> 1) << 2) | (wid & 1);   // B alpha-unit group

  short8 a[4][2], b[2][2];
  f32x4 acc[8][4] = {};

#define STAGE_A(buf, beta, tau) do{ \
    const int g_ = gA | ((beta) << 2); \
    const short* gp_ = Abase + (long)(g_ * 16) * K + (long)(tau) * 64; \
    gload16(gp_,      &lds[buf][0][(g_ * 2 + 0) * 512]); \
    gload16(gp_ + 32, &lds[buf][0][(g_ * 2 + 1) * 512]); \
  }while(0)
#define STAGE_B(buf, beta, tau) do{ \
    const int g_ = gB | ((beta) << 1); \
    const short* gp_ = Bbase + (long)(g_ * 16) * K + (long)(tau) * 64; \
    gload16(gp_,      &lds[buf][1][(g_ * 2 + 0) * 512]); \
    gload16(gp_ + 32, &lds[buf][1][(g_ * 2 + 1) * 512]); \
  }while(0)
#define LDA(buf, mh) do{ \
    _Pragma("unroll") \
    for (int j_ = 0; j_ < 4; j_++){ \
      const int o_ = (wr * 8 + (mh) * 4 + j_) * 1024 + fch * 128 + fr * 8; \
      a[j_][0] = *(const short8*)&lds[buf][0][o_]; \
      a[j_][1] = *(const short8*)&lds[buf][0][o_ + 512]; \
    } }while(0)
#define LDB(buf, nh) do{ \
    _Pragma("unroll") \
    for (int j_ = 0; j_ < 2; j_++){ \
      const int o_ = (wc * 4 + (nh) * 2 + j_) * 1024 + fch * 128 + fr * 8; \
      b[j_][0] = *(const short8*)&lds[buf][1][o_]; \
      b[j_][1] = *(const short8*)&lds[buf][1][o_ + 512]; \
    } }while(0)
#define SYNC_MF(mh, nh) do{ \
    __builtin_amdgcn_s_barrier(); \
    asm volatile("s_waitcnt lgkmcnt(0)" ::: "memory"); \
    __builtin_amdgcn_s_setprio(1); \
    _Pragma("unroll") \
    for (int j_ = 0; j_ < 4; j_++) \
      _Pragma("unroll") \
      for (int i_ = 0; i_ < 2; i_++){ \
        acc[(mh)*4+j_][(nh)*2+i_] = mfma16(a[j_][0], b[i_][0], acc[(mh)*4+j_][(nh)*2+i_]); \
        acc[(mh)*4+j_][(nh)*2+i_] = mfma16(a[j_][1], b[i_][1], acc[(mh)*4+j_][(nh)*2+i_]); \
      } \
    __builtin_amdgcn_s_setprio(0); \
    __builtin_amdgcn_s_barrier(); \
  }while(0)

  // prologue: tile0 all 4 units, then Aα(1), Bβ(1), Aβ(1); Bα(1) staged at p1.
  STAGE_A(0, 0, 0); STAGE_B(0, 0, 0); STAGE_B(0, 1, 0); STAGE_A(0, 1, 0);
  STAGE_A(1, 0, 1); STAGE_B(1, 1, 1); STAGE_A(1, 1, 1);
  asm volatile("s_waitcnt vmcnt(6)" ::: "memory");
  __builtin_amdgcn_s_barrier();

  for (int it = 0; it < nIter; ++it){
    const int t = it * 2;
    const int t2 = (t + 2 < nt) ? t + 2 : nt - 1;
    const int t3 = (t + 3 < nt) ? t + 3 : nt - 1;
    // p1
    LDA(0, 0); LDB(0, 0); STAGE_B(1, 0, t + 1);
    SYNC_MF(0, 0);
    // p2
    LDB(0, 1); STAGE_A(0, 0, t2);
    SYNC_MF(0, 1);
    // p3
    LDA(0, 1); STAGE_B(0, 1, t2);
    SYNC_MF(1, 1);
    // p4
    LDB(0, 0); STAGE_A(0, 1, t2);
    asm volatile("s_waitcnt vmcnt(6)" ::: "memory");
    SYNC_MF(1, 0);
    // p5
    LDA(1, 0); LDB(1, 0); STAGE_B(0, 0, t2);
    SYNC_MF(0, 0);
    // p6
    LDB(1, 1); STAGE_A(1, 0, t3);
    SYNC_MF(0, 1);
    // p7
    LDA(1, 1); STAGE_B(1, 1, t3);
    SYNC_MF(1, 1);
    // p8
    LDB(1, 0); STAGE_A(1, 1, t3);
    asm volatile("s_waitcnt vmcnt(6)" ::: "memory");
    SYNC_MF(1, 0);
  }
  asm volatile("s_waitcnt vmcnt(0)" ::: "memory");

#undef STAGE_A
#undef STAGE_B
#undef LDA
#undef LDB
#undef SYNC_MF

  const int rb0 = mb * 256 + wr * 128 + fch * 4;
  const int cb0 = nb * 256 + wc * 64 + fr;
  #pragma unroll
  for (int m = 0; m < 8; m++)
    #pragma unroll
    for (int n = 0; n < 4; n++)
      #pragma unroll
      for (int i = 0; i < 4; i++){
        long idx = (long)(rb0 + m * 16 + i) * N + (cb0 + n * 16);
        float v = acc[m][n][i];
        if constexpr (EPI == 0) Cf[idx] = v;
        else if constexpr (EPI == 1) Cb[idx] = (short)f2bf(v);
        else if constexpr (EPI == 3){
          float sg = 1.0f / (1.0f + __expf(-v));
          Cb[idx] = (short)f2bf(v * sg);
        } else {
          float g = bf2f(Xtra[idx]);
          Cb[idx] = (short)f2bf(g * v);
        }
      }
}

// ---------------- 128x128 GEMM (m97 structure, conflict-free LDS) ----------------
// Used for N=2048 outputs (Wo, Wdown). EPI 2 = f32 residual add.
template<int EPI>
__global__ __launch_bounds__(256)
void gemm_bt(const short* __restrict__ A, const short* __restrict__ Bt,
             float* __restrict__ Cf, short* __restrict__ Cb,
             const short* __restrict__ Xtra, int N, int K){
  __shared__ short As[4096];
  __shared__ short Bs[4096];
  const int tid = threadIdx.x;
  const int wave = tid >> 6, lane = tid & 63;
  const int wr = wave >> 1, wc = wave & 1;
  const int mb = blockIdx.y, nb = blockIdx.x;

  const int srow = lane & 15;
  const int scol = (lane >> 4) * 8;
  const short* ApL0 = A + (long)(mb * 128 + wave * 16 + srow) * K + scol;
  const short* ApL1 = ApL0 + (long)64 * K;
  const short* BpL0 = Bt + (long)(nb * 128 + wave * 16 + srow) * K + scol;
  const short* BpL1 = BpL0 + (long)64 * K;

  f32x4 acc[4][4] = {};
  const int fr = lane & 15, fch = lane >> 4;

  for (int kb = 0; kb < K; kb += 32){
    __syncthreads();
    gload16(ApL0 + kb, &As[wave * 512]);
    gload16(ApL1 + kb, &As[(4 + wave) * 512]);
    gload16(BpL0 + kb, &Bs[wave * 512]);
    gload16(BpL1 + kb, &Bs[(4 + wave) * 512]);
    __syncthreads();
    short8 a[4], b[4];
    #pragma unroll
    for (int m = 0; m < 4; m++)
      a[m] = *(const short8*)&As[(wr * 4 + m) * 512 + fch * 128 + fr * 8];
    #pragma unroll
    for (int n = 0; n < 4; n++)
      b[n] = *(const short8*)&Bs[(wc * 4 + n) * 512 + fch * 128 + fr * 8];
    #pragma unroll
    for (int m = 0; m < 4; m++)
      #pragma unroll
      for (int n = 0; n < 4; n++)
        acc[m][n] = mfma16(a[m], b[n], acc[m][n]);
  }

  const int rb = mb * 128 + wr * 64 + (lane >> 4) * 4;
  const int cb = nb * 128 + wc * 64 + (lane & 15);
  #pragma unroll
  for (int m = 0; m < 4; m++)
    #pragma unroll
    for (int n = 0; n < 4; n++)
      #pragma unroll
      for (int i = 0; i < 4; i++){
        long idx = (long)(rb + m * 16 + i) * N + (cb + n * 16);
        float v = acc[m][n][i];
        if constexpr (EPI == 0) Cf[idx] = v;
        else if constexpr (EPI == 1) Cb[idx] = (short)f2bf(v);
        else if constexpr (EPI == 2) Cf[idx] += v;
        else if constexpr (EPI == 3){
          float sg = 1.0f / (1.0f + __expf(-v));
          Cb[idx] = (short)f2bf(v * sg);
        } else {
          float g = bf2f(Xtra[idx]);
          Cb[idx] = (short)f2bf(g * v);
        }
      }
}

// ---------------- flash attention ----------------
__device__ __forceinline__ int qoff(int r, int cB){ return r * 256 + (cB ^ ((r & 7) << 4)); }
__device__ __forceinline__ int voff(int d, int cB){ return d * 128 + (cB ^ ((d & 7) << 4)); }
__device__ __forceinline__ int poff(int r, int cB){ return r * 128 + (cB ^ ((r & 7) << 4)); }

__global__ __launch_bounds__(256)
void attn_k(const short* __restrict__ qb, const short* __restrict__ kb,
            const short* __restrict__ vtb, short* __restrict__ ob){
  __shared__ short Qs[64 * 128];
  __shared__ short Ks[64 * 128];
  __shared__ short Vt[128 * 64];
  __shared__ short Ps[64 * 64];
  const int tid = threadIdx.x, wave = tid >> 6, lane = tid & 63;
  const int qt = blockIdx.x, head = blockIdx.y, kvh = head >> 1;
  const float scale = 0.08838834764831845f;  // 1/sqrt(128)

  {
    int r0 = tid >> 4, c16 = tid & 15;
    #pragma unroll
    for (int p = 0; p < 4; p++){
      int r = r0 + p * 16;
      u32x4 v = *(const u32x4*)&qb[(long)(qt * 64 + r) * QKVN + head * HDIM + c16 * 8];
      *(u32x4*)((char*)Qs + qoff(r, c16 * 16)) = v;
    }
  }

  float mrun[4] = {-1e30f, -1e30f, -1e30f, -1e30f};
  float lrun[4] = {0.f, 0.f, 0.f, 0.f};
  f32x4 accO[8] = {};

  for (int kt = 0; kt <= qt; kt++){
    __syncthreads();
    {
      int r0 = tid >> 4, c16 = tid & 15;
      #pragma unroll
      for (int p = 0; p < 4; p++){
        int r = r0 + p * 16;
        u32x4 v = *(const u32x4*)&kb[(long)(kt * 64 + r) * QKVN + kvh * HDIM + c16 * 8];
        *(u32x4*)((char*)Ks + qoff(r, c16 * 16)) = v;
      }
      int vr0 = tid >> 3, vc = tid & 7;
      #pragma unroll
      for (int p = 0; p < 4; p++){
        int d = vr0 + p * 32;
        u32x4 v = *(const u32x4*)&vtb[(long)(kvh * HDIM + d) * TS + kt * 64 + vc * 8];
        *(u32x4*)((char*)Vt + voff(d, vc * 16)) = v;
      }
    }
    __syncthreads();

    f32x4 sacc[4] = {};
    #pragma unroll
    for (int k4 = 0; k4 < 4; k4++){
      short8 aq = *(const short8*)((const char*)Qs +
                   qoff(wave * 16 + (lane & 15), k4 * 64 + (lane >> 4) * 16));
      #pragma unroll
      for (int n = 0; n < 4; n++){
        short8 bk = *(const short8*)((const char*)Ks +
                     qoff(n * 16 + (lane & 15), k4 * 64 + (lane >> 4) * 16));
        sacc[n] = mfma16(aq, bk, sacc[n]);
      }
    }

    const bool diag = (kt == qt);
    float mt[4] = {-1e30f, -1e30f, -1e30f, -1e30f};
    #pragma unroll
    for (int n = 0; n < 4; n++)
      #pragma unroll
      for (int i = 0; i < 4; i++){
        float v = sacc[n][i] * scale;
        if (diag){
          int rr = (lane >> 4) * 4 + i + wave * 16;
          int cc = n * 16 + (lane & 15);
          if (cc > rr) v = -1e30f;
        }
        sacc[n][i] = v;
        mt[i] = fmaxf(mt[i], v);
      }
    #pragma unroll
    for (int off = 1; off < 16; off <<= 1)
      #pragma unroll
      for (int i = 0; i < 4; i++) mt[i] = fmaxf(mt[i], __shfl_xor(mt[i], off));
    float alpha[4], rsum[4];
    #pragma unroll
    for (int i = 0; i < 4; i++){
      float mn = fmaxf(mrun[i], mt[i]);
      alpha[i] = __expf(mrun[i] - mn);
      mrun[i] = mn;
      rsum[i] = 0.f;
    }
    #pragma unroll
    for (int n = 0; n < 4; n++)
      #pragma unroll
      for (int i = 0; i < 4; i++){
        float p = __expf(sacc[n][i] - mrun[i]);
        sacc[n][i] = p;
        rsum[i] += p;
      }
    #pragma unroll
    for (int off = 1; off < 16; off <<= 1)
      #pragma unroll
      for (int i = 0; i < 4; i++) rsum[i] += __shfl_xor(rsum[i], off);
    #pragma unroll
    for (int i = 0; i < 4; i++) lrun[i] = lrun[i] * alpha[i] + rsum[i];

    #pragma unroll
    for (int n = 0; n < 4; n++)
      #pragma unroll
      for (int i = 0; i < 4; i++){
        int rr = wave * 16 + (lane >> 4) * 4 + i;
        int cc = n * 16 + (lane & 15);
        *(short*)((char*)Ps + poff(rr, cc * 2)) = (short)f2bf(sacc[n][i]);
      }

    #pragma unroll
    for (int n = 0; n < 8; n++)
      #pragma unroll
      for (int i = 0; i < 4; i++) accO[n][i] *= alpha[i];
    #pragma unroll
    for (int ks = 0; ks < 2; ks++){
      short8 ap = *(const short8*)((const char*)Ps +
                   poff(wave * 16 + (lane & 15), ks * 64 + (lane >> 4) * 16));
      #pragma unroll
      for (int n = 0; n < 8; n++){
        short8 bv = *(const short8*)((const char*)Vt +
                     voff(n * 16 + (lane & 15), ks * 64 + (lane >> 4) * 16));
        accO[n] = mfma16(ap, bv, accO[n]);
      }
    }
  }

  #pragma unroll
  for (int i = 0; i < 4; i++){
    float inv = 1.0f / lrun[i];
    int rr = qt * 64 + wave * 16 + (lane >> 4) * 4 + i;
    #pragma unroll
    for (int n = 0; n < 8; n++){
      int cc = head * HDIM + n * 16 + (lane & 15);
      ob[(long)rr * DM + cc] = (short)f2bf(accO[n][i] * inv);
    }
  }
}

// ---------------- host ----------------
extern "C" void kernel_launch(void* const* d_in, const int* in_sizes, int n_in,
                              void* d_out, int out_size, void* d_ws, size_t ws_size,
                              hipStream_t stream){
  (void)in_sizes; (void)n_in; (void)out_size; (void)ws_size;
  const int*   ids = (const int*)d_in[0];
  const float* E   = (const float*)d_in[1];
  const float* Wq  = (const float*)d_in[2];
  const float* Wk  = (const float*)d_in[3];
  const float* Wv  = (const float*)d_in[4];
  const float* Wo  = (const float*)d_in[5];
  const float* Wg  = (const float*)d_in[6];
  const float* Wu  = (const float*)d_in[7];
  const float* Wd  = (const float*)d_in[8];
  const float* nA  = (const float*)d_in[9];
  const float* nM  = (const float*)d_in[10];
  const float* nF  = (const float*)d_in[11];
  const float* LMH = (const float*)d_in[12];
  float* out = (float*)d_out;

  char* ws = (char*)d_ws;
  size_t off = 0;
  auto alloc = [&](size_t bytes){ void* p = ws + off; off += (bytes + 255) & ~(size_t)255; return p; };
  float* h    = (float*)alloc((size_t)TS * DM * 4);
  short* xb   = (short*)alloc((size_t)TS * DM * 2);
  short* qkvb = (short*)alloc((size_t)TS * QKVN * 2);     // [S][4096]: q | k | v
  short* vtb  = (short*)alloc((size_t)NKVH * HDIM * TS * 2);
  short* obuf = (short*)alloc((size_t)TS * DM * 2);
  short* sg   = (short*)alloc((size_t)TS * FFD * 2);
  short* actb = (short*)alloc((size_t)TS * FFD * 2);
  float* cosT = (float*)alloc((size_t)TS * 64 * 4);
  float* sinT = (float*)alloc((size_t)TS * 64 * 4);
  short* wT   = (short*)alloc((size_t)NVOC * DM * 2);

  rope_tables_k<<<512, 256, 0, stream>>>(cosT, sinT);
  embed_k<<<TS, 256, 0, stream>>>(ids, E, h);

  for (int l = 0; l < 2; l++){
    rmsnorm_k<<<TS, 256, 0, stream>>>(h, nA + (size_t)l * DM, xb);
    // fused QKV: Bt rows [0,2048)=Wq^T, [2048,3072)=Wk^T, [3072,4096)=Wv^T
    transpose_k<<<dim3(32, 32), 256, 0, stream>>>(Wq + (size_t)l * DM * DM, wT, DM, DM);
    transpose_k<<<dim3(16, 32), 256, 0, stream>>>(Wk + (size_t)l * DM * 1024, wT + (size_t)2048 * DM, DM, 1024);
    transpose_k<<<dim3(16, 32), 256, 0, stream>>>(Wv + (size_t)l * DM * 1024, wT + (size_t)3072 * DM, DM, 1024);
    gemm256<1><<<dim3(16, 8), 512, 0, stream>>>(xb, wT, nullptr, qkvb, nullptr, QKVN, DM);
    // RoPE (in place on bf16) on q and k slices; V transpose
    rope_apply_k<<<8192, 256, 0, stream>>>(qkvb, cosT, sinT, NHEAD, QKVN, 0);
    rope_apply_k<<<4096, 256, 0, stream>>>(qkvb, cosT, sinT, NKVH, QKVN, 2048);
    vtrans_k<<<dim3(32, 8), 256, 0, stream>>>(qkvb + 3072, vtb, QKVN);
    // attention
    attn_k<<<dim3(32, 16), 256, 0, stream>>>(qkvb, qkvb + 2048, vtb, obuf);
    // h += o @ Wo[l]
    transpose_k<<<dim3(32, 32), 256, 0, stream>>>(Wo + (size_t)l * DM * DM, wT, DM, DM);
    gemm_bt<2><<<dim3(16, 16), 256, 0, stream>>>(obuf, wT, h, nullptr, nullptr, DM, DM);
    // MLP
    rmsnorm_k<<<TS, 256, 0, stream>>>(h, nM + (size_t)l * DM, xb);
    transpose_k<<<dim3(128, 32), 256, 0, stream>>>(Wg + (size_t)l * DM * FFD, wT, DM, FFD);
    gemm256<3><<<dim3(32, 8), 512, 0, stream>>>(xb, wT, nullptr, sg, nullptr, FFD, DM);
    transpose_k<<<dim3(128, 32), 256, 0, stream>>>(Wu + (size_t)l * DM * FFD, wT, DM, FFD);
    gemm256<4><<<dim3(32, 8), 512, 0, stream>>>(xb, wT, nullptr, actb, sg, FFD, DM);
    transpose_k<<<dim3(32, 128), 256, 0, stream>>>(Wd + (size_t)l * FFD * DM, wT, FFD, DM);
    gemm_bt<2><<<dim3(16, 16), 256, 0, stream>>>(actb, wT, h, nullptr, nullptr, DM, FFD);
  }

  rmsnorm_k<<<TS, 256, 0, stream>>>(h, nF, xb);
  transpose_k<<<dim3(500, 32), 256, 0, stream>>>(LMH, wT, DM, NVOC);
  gemm256<0><<<dim3(125, 8), 512, 0, stream>>>(xb, wT, out, nullptr, nullptr, NVOC, DM);
}

// Round 6
// 1542.522 us; speedup vs baseline: 1.5172x; 1.1914x over previous
//
#include <hip/hip_runtime.h>
#include <cstdint>
#include <cstddef>

typedef __attribute__((ext_vector_type(4))) float f32x4;
typedef __attribute__((ext_vector_type(8))) short short8;
typedef __attribute__((ext_vector_type(4))) unsigned int u32x4;

static const int TS = 2048;      // sequence length
static const int DM = 2048;      // d_model
static const int NHEAD = 16, NKVH = 8, HDIM = 128;
static const int FFD = 8192;
static const int NVOC = 32000;
static const int QKVN = 4096;    // fused QKV output width (2048 q + 1024 k + 1024 v)

__device__ __forceinline__ unsigned short f2bf(float f){
  unsigned int u = __builtin_bit_cast(unsigned int, f);
  u += 0x7FFFu + ((u >> 16) & 1u);
  return (unsigned short)(u >> 16);
}
__device__ __forceinline__ float bf2f(short h){
  unsigned int u = ((unsigned int)(unsigned short)h) << 16;
  return __builtin_bit_cast(float, u);
}
__device__ __forceinline__ f32x4 mfma16(short8 a, short8 b, f32x4 c){
  return __builtin_amdgcn_mfma_f32_16x16x32_bf16(a, b, c, 0, 0, 0);
}
__device__ __forceinline__ void gload16(const void* g, void* l){
  __builtin_amdgcn_global_load_lds(
      (const __attribute__((address_space(1))) unsigned int*)g,
      (__attribute__((address_space(3))) unsigned int*)l, 16, 0, 0);
}

// ---------------- RoPE tables ----------------
__global__ void rope_tables_k(float* __restrict__ cosT, float* __restrict__ sinT){
  int idx = blockIdx.x * 256 + threadIdx.x;   // TS*64 entries
  int s = idx >> 6, j = idx & 63;
  float inv = exp2f(-(float)j * (13.287712379549449f / 64.0f)); // 10000^(-j/64)
  float ang = (float)s * inv;
  cosT[idx] = cosf(ang);
  sinT[idx] = sinf(ang);
}

// ---------------- embedding gather ----------------
__global__ void embed_k(const int* __restrict__ ids, const float* __restrict__ E,
                        float* __restrict__ h){
  int s = blockIdx.x, tid = threadIdx.x;
  long id = ids[s];
  const f32x4* src = (const f32x4*)(E + id * (long)DM);
  f32x4* dst = (f32x4*)(h + (long)s * DM);
  dst[tid] = src[tid];
  dst[tid + 256] = src[tid + 256];
}

// ---------------- RMSNorm (f32 in -> bf16 out) ----------------
__global__ void rmsnorm_k(const float* __restrict__ x, const float* __restrict__ w,
                          short* __restrict__ out){
  int s = blockIdx.x, tid = threadIdx.x;
  const float* row = x + (long)s * DM;
  f32x4 v0 = *(const f32x4*)&row[tid * 8];
  f32x4 v1 = *(const f32x4*)&row[tid * 8 + 4];
  float ss = v0[0]*v0[0] + v0[1]*v0[1] + v0[2]*v0[2] + v0[3]*v0[3]
           + v1[0]*v1[0] + v1[1]*v1[1] + v1[2]*v1[2] + v1[3]*v1[3];
  #pragma unroll
  for (int off = 32; off; off >>= 1) ss += __shfl_xor(ss, off);
  __shared__ float sred[4];
  int wave = tid >> 6, lane = tid & 63;
  if (lane == 0) sred[wave] = ss;
  __syncthreads();
  float tot = sred[0] + sred[1] + sred[2] + sred[3];
  float r = rsqrtf(tot * (1.0f / (float)DM) + 1e-5f);
  f32x4 w0 = *(const f32x4*)&w[tid * 8];
  f32x4 w1 = *(const f32x4*)&w[tid * 8 + 4];
  short8 o;
  #pragma unroll
  for (int j = 0; j < 4; j++) o[j] = (short)f2bf(v0[j] * r * w0[j]);
  #pragma unroll
  for (int j = 0; j < 4; j++) o[4 + j] = (short)f2bf(v1[j] * r * w1[j]);
  *(short8*)&out[(long)s * DM + tid * 8] = o;
}

// ---------------- weight transpose+convert: B[K][N] f32 -> Bt[N][K] bf16 ----------------
__global__ void transpose_k(const float* __restrict__ B, short* __restrict__ Bt,
                            int K, int N){
  __shared__ float t[64][65];
  int tid = threadIdx.x;
  int kb = blockIdx.y * 64, nb = blockIdx.x * 64;
  int r0 = tid >> 4, c4 = tid & 15;
  #pragma unroll
  for (int p = 0; p < 4; p++){
    int r = r0 + p * 16;
    f32x4 v = *(const f32x4*)&B[(long)(kb + r) * N + nb + c4 * 4];
    t[r][c4*4+0] = v[0]; t[r][c4*4+1] = v[1]; t[r][c4*4+2] = v[2]; t[r][c4*4+3] = v[3];
  }
  __syncthreads();
  int n0 = tid >> 3, k0 = (tid & 7) * 8;
  #pragma unroll
  for (int p = 0; p < 2; p++){
    int n = n0 + p * 32;
    short8 o;
    #pragma unroll
    for (int j = 0; j < 8; j++) o[j] = (short)f2bf(t[k0 + j][n]);
    *(short8*)&Bt[(long)(nb + n) * K + kb + k0] = o;
  }
}

// ---------------- V transpose: vsrc[s][kv*HD+d] (stride) -> vtb[kv][d][s] (bf16) ----------------
__global__ void vtrans_k(const short* __restrict__ vb, short* __restrict__ vtb, int stride){
  int s0 = blockIdx.x * 64, kv = blockIdx.y;
  int tid = threadIdx.x;
  int s = s0 + (tid & 63);
  int d0 = (tid >> 6) * 8;
  #pragma unroll
  for (int p = 0; p < 4; p++){
    int d = d0 + p * 32;
    short8 v = *(const short8*)&vb[(long)s * stride + kv * HDIM + d];
    #pragma unroll
    for (int j = 0; j < 8; j++)
      vtb[(long)(kv * HDIM + d + j) * TS + s] = v[j];
  }
}

// ---------------- RoPE apply (in-place bf16) ----------------
__global__ void rope_apply_k(short* __restrict__ buf, const float* __restrict__ cosT,
                             const float* __restrict__ sinT, int nh, int stride, int coloff){
  int idx = blockIdx.x * 256 + threadIdx.x;  // TS*nh*64
  int j = idx & 63;
  int t = idx >> 6;
  int hh = t % nh;
  int s = t / nh;
  long base = (long)s * stride + coloff + hh * HDIM + j;
  float c = cosT[s * 64 + j], sn = sinT[s * 64 + j];
  float x1 = bf2f(buf[base]), x2 = bf2f(buf[base + 64]);
  buf[base]      = (short)f2bf(x1 * c - x2 * sn);
  buf[base + 64] = (short)f2bf(x2 * c + x1 * sn);
}

// ---------------- split-K reduce: h += p0+p1+p2+p3 (f32, deterministic) ----------------
__global__ void reduce4_k(const float* __restrict__ p, float* __restrict__ h){
  const long stride = (long)TS * DM;   // 4,194,304
  long i = ((long)blockIdx.x * 256 + threadIdx.x) * 4;
  f32x4 a = *(const f32x4*)&h[i];
  f32x4 v0 = *(const f32x4*)&p[i];
  f32x4 v1 = *(const f32x4*)&p[i + stride];
  f32x4 v2 = *(const f32x4*)&p[i + 2 * stride];
  f32x4 v3 = *(const f32x4*)&p[i + 3 * stride];
  a = a + ((v0 + v1) + (v2 + v3));
  *(f32x4*)&h[i] = a;
}

// ================= 256x256 8-phase GEMM (T1+T2-layout+T3/T4/T5) =================
// C[M,N] = A[M,K](bf16, row stride lda) x Bt[N,K](bf16, row stride ldb).
// 512 threads = 8 waves (2Mx4N), BK=64, 2 K-tiles/iter, 128 KiB LDS,
// fragment-major conflict-free subtiles, counted vmcnt(6) at p4/p8,
// raw s_barrier pairs, setprio around MFMA. 1D grid (nwg%8==0), bijective
// XCD swizzle + mb-fastest (8 consecutive blocks share one B panel in L2).
// blockIdx.y = split-K slice (pointers pre-offset by y*K).
// EPI: 0 f32 store, 1 bf16, 3 bf16 silu, 4 bf16 Xtra*acc, 5 f32 partial@slice
template<int EPI>
__global__ __launch_bounds__(512, 2)
void gemm256(const short* __restrict__ A, int lda,
             const short* __restrict__ Bt, int ldb,
             float* __restrict__ Cf, short* __restrict__ Cb,
             const short* __restrict__ Xtra, int N, int K){
  __shared__ short lds[2][2][16384];   // [buf][op][16 subtiles x 1 KiB]
  const int tid = threadIdx.x;
  const int wid = tid >> 6, lane = tid & 63;
  const int wr = wid >> 2, wc = wid & 3;
  const int fr = lane & 15, fch = lane >> 4;
  const int nt = K >> 6;
  const int nIter = nt >> 1;

  // split-K slice offset (blockIdx.y = z)
  const int z = blockIdx.y;
  A  += (long)z * K;
  Bt += (long)z * K;

  // bijective XCD swizzle (nwg % 8 == 0 for all our shapes) + mb-fastest
  const int nbt = N >> 8;
  const int nwg = nbt << 3;            // 8 mb-tiles (M = 2048)
  const int q = nwg >> 3;
  const int swz = (blockIdx.x & 7) * q + (blockIdx.x >> 3);
  const int mb = swz & 7, nb = swz >> 3;

  // per-lane global staging base: row (+fr), k-chunk (+fch*8)
  const short* Abase = A  + (long)(mb * 256 + fr) * lda + fch * 8;
  const short* Bbase = Bt + (long)(nb * 256 + fr) * ldb + fch * 8;
  const int gA = ((wid >> 2) << 3) | (wid & 3);   // A alpha-unit group for this wave
  const int gB = ((wid >> 1) << 2) | (wid & 1);   // B alpha-unit group

  short8 a[4][2], b[2][2];
  f32x4 acc[8][4] = {};

#define STAGE_A(buf, beta, tau) do{ \
    const int g_ = gA | ((beta) << 2); \
    const short* gp_ = Abase + (long)(g_ * 16) * lda + (long)(tau) * 64; \
    gload16(gp_,      &lds[buf][0][(g_ * 2 + 0) * 512]); \
    gload16(gp_ + 32, &lds[buf][0][(g_ * 2 + 1) * 512]); \
  }while(0)
#define STAGE_B(buf, beta, tau) do{ \
    const int g_ = gB | ((beta) << 1); \
    const short* gp_ = Bbase + (long)(g_ * 16) * ldb + (long)(tau) * 64; \
    gload16(gp_,      &lds[buf][1][(g_ * 2 + 0) * 512]); \
    gload16(gp_ + 32, &lds[buf][1][(g_ * 2 + 1) * 512]); \
  }while(0)
#define LDA(buf, mh) do{ \
    _Pragma("unroll") \
    for (int j_ = 0; j_ < 4; j_++){ \
      const int o_ = (wr * 8 + (mh) * 4 + j_) * 1024 + fch * 128 + fr * 8; \
      a[j_][0] = *(const short8*)&lds[buf][0][o_]; \
      a[j_][1] = *(const short8*)&lds[buf][0][o_ + 512]; \
    } }while(0)
#define LDB(buf, nh) do{ \
    _Pragma("unroll") \
    for (int j_ = 0; j_ < 2; j_++){ \
      const int o_ = (wc * 4 + (nh) * 2 + j_) * 1024 + fch * 128 + fr * 8; \
      b[j_][0] = *(const short8*)&lds[buf][1][o_]; \
      b[j_][1] = *(const short8*)&lds[buf][1][o_ + 512]; \
    } }while(0)
#define SYNC_MF(mh, nh) do{ \
    __builtin_amdgcn_s_barrier(); \
    asm volatile("s_waitcnt lgkmcnt(0)" ::: "memory"); \
    __builtin_amdgcn_s_setprio(1); \
    _Pragma("unroll") \
    for (int j_ = 0; j_ < 4; j_++) \
      _Pragma("unroll") \
      for (int i_ = 0; i_ < 2; i_++){ \
        acc[(mh)*4+j_][(nh)*2+i_] = mfma16(a[j_][0], b[i_][0], acc[(mh)*4+j_][(nh)*2+i_]); \
        acc[(mh)*4+j_][(nh)*2+i_] = mfma16(a[j_][1], b[i_][1], acc[(mh)*4+j_][(nh)*2+i_]); \
      } \
    __builtin_amdgcn_s_setprio(0); \
    __builtin_amdgcn_s_barrier(); \
  }while(0)

  // prologue: tile0 all 4 units, then Aα(1), Bβ(1), Aβ(1); Bα(1) staged at p1.
  STAGE_A(0, 0, 0); STAGE_B(0, 0, 0); STAGE_B(0, 1, 0); STAGE_A(0, 1, 0);
  STAGE_A(1, 0, 1); STAGE_B(1, 1, 1); STAGE_A(1, 1, 1);
  asm volatile("s_waitcnt vmcnt(6)" ::: "memory");
  __builtin_amdgcn_s_barrier();

  for (int it = 0; it < nIter; ++it){
    const int t = it * 2;
    const int t2 = (t + 2 < nt) ? t + 2 : nt - 1;
    const int t3 = (t + 3 < nt) ? t + 3 : nt - 1;
    // p1
    LDA(0, 0); LDB(0, 0); STAGE_B(1, 0, t + 1);
    SYNC_MF(0, 0);
    // p2
    LDB(0, 1); STAGE_A(0, 0, t2);
    SYNC_MF(0, 1);
    // p3
    LDA(0, 1); STAGE_B(0, 1, t2);
    SYNC_MF(1, 1);
    // p4
    LDB(0, 0); STAGE_A(0, 1, t2);
    asm volatile("s_waitcnt vmcnt(6)" ::: "memory");
    SYNC_MF(1, 0);
    // p5
    LDA(1, 0); LDB(1, 0); STAGE_B(0, 0, t2);
    SYNC_MF(0, 0);
    // p6
    LDB(1, 1); STAGE_A(1, 0, t3);
    SYNC_MF(0, 1);
    // p7
    LDA(1, 1); STAGE_B(1, 1, t3);
    SYNC_MF(1, 1);
    // p8
    LDB(1, 0); STAGE_A(1, 1, t3);
    asm volatile("s_waitcnt vmcnt(6)" ::: "memory");
    SYNC_MF(1, 0);
  }
  asm volatile("s_waitcnt vmcnt(0)" ::: "memory");

#undef STAGE_A
#undef STAGE_B
#undef LDA
#undef LDB
#undef SYNC_MF

  const int rb0 = mb * 256 + wr * 128 + fch * 4;
  const int cb0 = nb * 256 + wc * 64 + fr;
  const long pbase = (EPI == 5) ? (long)z * ((long)TS * N) : 0;
  #pragma unroll
  for (int m = 0; m < 8; m++)
    #pragma unroll
    for (int n = 0; n < 4; n++)
      #pragma unroll
      for (int i = 0; i < 4; i++){
        long idx = (long)(rb0 + m * 16 + i) * N + (cb0 + n * 16);
        float v = acc[m][n][i];
        if constexpr (EPI == 0) Cf[idx] = v;
        else if constexpr (EPI == 1) Cb[idx] = (short)f2bf(v);
        else if constexpr (EPI == 3){
          float sg = 1.0f / (1.0f + __expf(-v));
          Cb[idx] = (short)f2bf(v * sg);
        } else if constexpr (EPI == 4){
          float g = bf2f(Xtra[idx]);
          Cb[idx] = (short)f2bf(g * v);
        } else {
          Cf[pbase + idx] = v;
        }
      }
}

// ---------------- 128x128 GEMM (m97 structure, conflict-free LDS) ----------------
// Used for Wo (N=2048). EPI 2 = f32 residual add.
template<int EPI>
__global__ __launch_bounds__(256)
void gemm_bt(const short* __restrict__ A, const short* __restrict__ Bt,
             float* __restrict__ Cf, short* __restrict__ Cb,
             const short* __restrict__ Xtra, int N, int K){
  __shared__ short As[4096];
  __shared__ short Bs[4096];
  const int tid = threadIdx.x;
  const int wave = tid >> 6, lane = tid & 63;
  const int wr = wave >> 1, wc = wave & 1;
  const int mb = blockIdx.y, nb = blockIdx.x;

  const int srow = lane & 15;
  const int scol = (lane >> 4) * 8;
  const short* ApL0 = A + (long)(mb * 128 + wave * 16 + srow) * K + scol;
  const short* ApL1 = ApL0 + (long)64 * K;
  const short* BpL0 = Bt + (long)(nb * 128 + wave * 16 + srow) * K + scol;
  const short* BpL1 = BpL0 + (long)64 * K;

  f32x4 acc[4][4] = {};
  const int fr = lane & 15, fch = lane >> 4;

  for (int kb = 0; kb < K; kb += 32){
    __syncthreads();
    gload16(ApL0 + kb, &As[wave * 512]);
    gload16(ApL1 + kb, &As[(4 + wave) * 512]);
    gload16(BpL0 + kb, &Bs[wave * 512]);
    gload16(BpL1 + kb, &Bs[(4 + wave) * 512]);
    __syncthreads();
    short8 a[4], b[4];
    #pragma unroll
    for (int m = 0; m < 4; m++)
      a[m] = *(const short8*)&As[(wr * 4 + m) * 512 + fch * 128 + fr * 8];
    #pragma unroll
    for (int n = 0; n < 4; n++)
      b[n] = *(const short8*)&Bs[(wc * 4 + n) * 512 + fch * 128 + fr * 8];
    #pragma unroll
    for (int m = 0; m < 4; m++)
      #pragma unroll
      for (int n = 0; n < 4; n++)
        acc[m][n] = mfma16(a[m], b[n], acc[m][n]);
  }

  const int rb = mb * 128 + wr * 64 + (lane >> 4) * 4;
  const int cb = nb * 128 + wc * 64 + (lane & 15);
  #pragma unroll
  for (int m = 0; m < 4; m++)
    #pragma unroll
    for (int n = 0; n < 4; n++)
      #pragma unroll
      for (int i = 0; i < 4; i++){
        long idx = (long)(rb + m * 16 + i) * N + (cb + n * 16);
        float v = acc[m][n][i];
        if constexpr (EPI == 0) Cf[idx] = v;
        else if constexpr (EPI == 1) Cb[idx] = (short)f2bf(v);
        else if constexpr (EPI == 2) Cf[idx] += v;
        else if constexpr (EPI == 3){
          float sg = 1.0f / (1.0f + __expf(-v));
          Cb[idx] = (short)f2bf(v * sg);
        } else {
          float g = bf2f(Xtra[idx]);
          Cb[idx] = (short)f2bf(g * v);
        }
      }
}

// ---------------- flash attention ----------------
__device__ __forceinline__ int qoff(int r, int cB){ return r * 256 + (cB ^ ((r & 7) << 4)); }
__device__ __forceinline__ int voff(int d, int cB){ return d * 128 + (cB ^ ((d & 7) << 4)); }
__device__ __forceinline__ int poff(int r, int cB){ return r * 128 + (cB ^ ((r & 7) << 4)); }

__global__ __launch_bounds__(256)
void attn_k(const short* __restrict__ qb, const short* __restrict__ kb,
            const short* __restrict__ vtb, short* __restrict__ ob){
  __shared__ short Qs[64 * 128];
  __shared__ short Ks[64 * 128];
  __shared__ short Vt[128 * 64];
  __shared__ short Ps[64 * 64];
  const int tid = threadIdx.x, wave = tid >> 6, lane = tid & 63;
  const int qt = blockIdx.x, head = blockIdx.y, kvh = head >> 1;
  const float scale = 0.08838834764831845f;  // 1/sqrt(128)

  {
    int r0 = tid >> 4, c16 = tid & 15;
    #pragma unroll
    for (int p = 0; p < 4; p++){
      int r = r0 + p * 16;
      u32x4 v = *(const u32x4*)&qb[(long)(qt * 64 + r) * QKVN + head * HDIM + c16 * 8];
      *(u32x4*)((char*)Qs + qoff(r, c16 * 16)) = v;
    }
  }

  float mrun[4] = {-1e30f, -1e30f, -1e30f, -1e30f};
  float lrun[4] = {0.f, 0.f, 0.f, 0.f};
  f32x4 accO[8] = {};

  for (int kt = 0; kt <= qt; kt++){
    __syncthreads();
    {
      int r0 = tid >> 4, c16 = tid & 15;
      #pragma unroll
      for (int p = 0; p < 4; p++){
        int r = r0 + p * 16;
        u32x4 v = *(const u32x4*)&kb[(long)(kt * 64 + r) * QKVN + kvh * HDIM + c16 * 8];
        *(u32x4*)((char*)Ks + qoff(r, c16 * 16)) = v;
      }
      int vr0 = tid >> 3, vc = tid & 7;
      #pragma unroll
      for (int p = 0; p < 4; p++){
        int d = vr0 + p * 32;
        u32x4 v = *(const u32x4*)&vtb[(long)(kvh * HDIM + d) * TS + kt * 64 + vc * 8];
        *(u32x4*)((char*)Vt + voff(d, vc * 16)) = v;
      }
    }
    __syncthreads();

    f32x4 sacc[4] = {};
    #pragma unroll
    for (int k4 = 0; k4 < 4; k4++){
      short8 aq = *(const short8*)((const char*)Qs +
                   qoff(wave * 16 + (lane & 15), k4 * 64 + (lane >> 4) * 16));
      #pragma unroll
      for (int n = 0; n < 4; n++){
        short8 bk = *(const short8*)((const char*)Ks +
                     qoff(n * 16 + (lane & 15), k4 * 64 + (lane >> 4) * 16));
        sacc[n] = mfma16(aq, bk, sacc[n]);
      }
    }

    const bool diag = (kt == qt);
    float mt[4] = {-1e30f, -1e30f, -1e30f, -1e30f};
    #pragma unroll
    for (int n = 0; n < 4; n++)
      #pragma unroll
      for (int i = 0; i < 4; i++){
        float v = sacc[n][i] * scale;
        if (diag){
          int rr = (lane >> 4) * 4 + i + wave * 16;
          int cc = n * 16 + (lane & 15);
          if (cc > rr) v = -1e30f;
        }
        sacc[n][i] = v;
        mt[i] = fmaxf(mt[i], v);
      }
    #pragma unroll
    for (int off = 1; off < 16; off <<= 1)
      #pragma unroll
      for (int i = 0; i < 4; i++) mt[i] = fmaxf(mt[i], __shfl_xor(mt[i], off));
    float alpha[4], rsum[4];
    #pragma unroll
    for (int i = 0; i < 4; i++){
      float mn = fmaxf(mrun[i], mt[i]);
      alpha[i] = __expf(mrun[i] - mn);
      mrun[i] = mn;
      rsum[i] = 0.f;
    }
    #pragma unroll
    for (int n = 0; n < 4; n++)
      #pragma unroll
      for (int i = 0; i < 4; i++){
        float p = __expf(sacc[n][i] - mrun[i]);
        sacc[n][i] = p;
        rsum[i] += p;
      }
    #pragma unroll
    for (int off = 1; off < 16; off <<= 1)
      #pragma unroll
      for (int i = 0; i < 4; i++) rsum[i] += __shfl_xor(rsum[i], off);
    #pragma unroll
    for (int i = 0; i < 4; i++) lrun[i] = lrun[i] * alpha[i] + rsum[i];

    #pragma unroll
    for (int n = 0; n < 4; n++)
      #pragma unroll
      for (int i = 0; i < 4; i++){
        int rr = wave * 16 + (lane >> 4) * 4 + i;
        int cc = n * 16 + (lane & 15);
        *(short*)((char*)Ps + poff(rr, cc * 2)) = (short)f2bf(sacc[n][i]);
      }

    #pragma unroll
    for (int n = 0; n < 8; n++)
      #pragma unroll
      for (int i = 0; i < 4; i++) accO[n][i] *= alpha[i];
    #pragma unroll
    for (int ks = 0; ks < 2; ks++){
      short8 ap = *(const short8*)((const char*)Ps +
                   poff(wave * 16 + (lane & 15), ks * 64 + (lane >> 4) * 16));
      #pragma unroll
      for (int n = 0; n < 8; n++){
        short8 bv = *(const short8*)((const char*)Vt +
                     voff(n * 16 + (lane & 15), ks * 64 + (lane >> 4) * 16));
        accO[n] = mfma16(ap, bv, accO[n]);
      }
    }
  }

  #pragma unroll
  for (int i = 0; i < 4; i++){
    float inv = 1.0f / lrun[i];
    int rr = qt * 64 + wave * 16 + (lane >> 4) * 4 + i;
    #pragma unroll
    for (int n = 0; n < 8; n++){
      int cc = head * HDIM + n * 16 + (lane & 15);
      ob[(long)rr * DM + cc] = (short)f2bf(accO[n][i] * inv);
    }
  }
}

// ---------------- host ----------------
extern "C" void kernel_launch(void* const* d_in, const int* in_sizes, int n_in,
                              void* d_out, int out_size, void* d_ws, size_t ws_size,
                              hipStream_t stream){
  (void)in_sizes; (void)n_in; (void)out_size; (void)ws_size;
  const int*   ids = (const int*)d_in[0];
  const float* E   = (const float*)d_in[1];
  const float* Wq  = (const float*)d_in[2];
  const float* Wk  = (const float*)d_in[3];
  const float* Wv  = (const float*)d_in[4];
  const float* Wo  = (const float*)d_in[5];
  const float* Wg  = (const float*)d_in[6];
  const float* Wu  = (const float*)d_in[7];
  const float* Wd  = (const float*)d_in[8];
  const float* nA  = (const float*)d_in[9];
  const float* nM  = (const float*)d_in[10];
  const float* nF  = (const float*)d_in[11];
  const float* LMH = (const float*)d_in[12];
  float* out = (float*)d_out;

  char* ws = (char*)d_ws;
  size_t off = 0;
  auto alloc = [&](size_t bytes){ void* p = ws + off; off += (bytes + 255) & ~(size_t)255; return p; };
  float* h    = (float*)alloc((size_t)TS * DM * 4);
  short* xb   = (short*)alloc((size_t)TS * DM * 2);
  short* qkvb = (short*)alloc((size_t)TS * QKVN * 2);     // [S][4096]: q | k | v
  short* vtb  = (short*)alloc((size_t)NKVH * HDIM * TS * 2);
  short* obuf = (short*)alloc((size_t)TS * DM * 2);
  short* sg   = (short*)alloc((size_t)TS * FFD * 2);
  short* actb = (short*)alloc((size_t)TS * FFD * 2);
  float* cosT = (float*)alloc((size_t)TS * 64 * 4);
  float* sinT = (float*)alloc((size_t)TS * 64 * 4);
  short* wT   = (short*)alloc((size_t)NVOC * DM * 2);     // 131 MB; tail reused for split-K partials
  // split-K partials: 4 x [TS][DM] f32 = 67.1 MB, placed 36 MB into wT
  // (WdT occupies only the first 33.6 MB of wT during down-proj)
  float* pPart = (float*)((char*)wT + (size_t)36 * 1024 * 1024);

  rope_tables_k<<<512, 256, 0, stream>>>(cosT, sinT);
  embed_k<<<TS, 256, 0, stream>>>(ids, E, h);

  for (int l = 0; l < 2; l++){
    rmsnorm_k<<<TS, 256, 0, stream>>>(h, nA + (size_t)l * DM, xb);
    // fused QKV: Bt rows [0,2048)=Wq^T, [2048,3072)=Wk^T, [3072,4096)=Wv^T
    transpose_k<<<dim3(32, 32), 256, 0, stream>>>(Wq + (size_t)l * DM * DM, wT, DM, DM);
    transpose_k<<<dim3(16, 32), 256, 0, stream>>>(Wk + (size_t)l * DM * 1024, wT + (size_t)2048 * DM, DM, 1024);
    transpose_k<<<dim3(16, 32), 256, 0, stream>>>(Wv + (size_t)l * DM * 1024, wT + (size_t)3072 * DM, DM, 1024);
    gemm256<1><<<dim3(128), 512, 0, stream>>>(xb, DM, wT, DM, nullptr, qkvb, nullptr, QKVN, DM);
    // RoPE (in place on bf16) on q and k slices; V transpose
    rope_apply_k<<<8192, 256, 0, stream>>>(qkvb, cosT, sinT, NHEAD, QKVN, 0);
    rope_apply_k<<<4096, 256, 0, stream>>>(qkvb, cosT, sinT, NKVH, QKVN, 2048);
    vtrans_k<<<dim3(32, 8), 256, 0, stream>>>(qkvb + 3072, vtb, QKVN);
    // attention
    attn_k<<<dim3(32, 16), 256, 0, stream>>>(qkvb, qkvb + 2048, vtb, obuf);
    // h += o @ Wo[l]
    transpose_k<<<dim3(32, 32), 256, 0, stream>>>(Wo + (size_t)l * DM * DM, wT, DM, DM);
    gemm_bt<2><<<dim3(16, 16), 256, 0, stream>>>(obuf, wT, h, nullptr, nullptr, DM, DM);
    // MLP
    rmsnorm_k<<<TS, 256, 0, stream>>>(h, nM + (size_t)l * DM, xb);
    transpose_k<<<dim3(128, 32), 256, 0, stream>>>(Wg + (size_t)l * DM * FFD, wT, DM, FFD);
    gemm256<3><<<dim3(256), 512, 0, stream>>>(xb, DM, wT, DM, nullptr, sg, nullptr, FFD, DM);
    transpose_k<<<dim3(128, 32), 256, 0, stream>>>(Wu + (size_t)l * DM * FFD, wT, DM, FFD);
    gemm256<4><<<dim3(256), 512, 0, stream>>>(xb, DM, wT, DM, nullptr, actb, sg, FFD, DM);
    // down-proj: split-K=4 on gemm256 (full GPU), partials + deterministic reduce
    transpose_k<<<dim3(32, 128), 256, 0, stream>>>(Wd + (size_t)l * FFD * DM, wT, FFD, DM);
    gemm256<5><<<dim3(64, 4), 512, 0, stream>>>(actb, FFD, wT, FFD, pPart, nullptr, nullptr, DM, FFD / 4);
    reduce4_k<<<4096, 256, 0, stream>>>(pPart, h);
  }

  rmsnorm_k<<<TS, 256, 0, stream>>>(h, nF, xb);
  transpose_k<<<dim3(500, 32), 256, 0, stream>>>(LMH, wT, DM, NVOC);
  gemm256<0><<<dim3(1000), 512, 0, stream>>>(xb, DM, wT, DM, out, nullptr, nullptr, NVOC, DM);
}